// Round 1
// baseline (237.252 us; speedup 1.0000x reference)
//
#include <hip/hip_runtime.h>
#include <hip/hip_bf16.h>
#include <stdint.h>

#define B_    2
#define S_    2048
#define D_    1024
#define H_    16
#define DH_   64
#define MTOT  (B_*S_)     // 4096
#define NQKV  (3*D_)      // 3072

typedef __attribute__((ext_vector_type(8))) short  bf16x8;
typedef __attribute__((ext_vector_type(4))) float  f32x4;
typedef __attribute__((ext_vector_type(8))) unsigned short u16x8;
typedef unsigned short ushort_t;

__device__ __forceinline__ ushort_t f2bf(float f) {
  union { float f; unsigned int i; } v; v.f = f;
  unsigned int r = v.i + 0x7FFF + ((v.i >> 16) & 1);
  return (ushort_t)(r >> 16);
}

__device__ __forceinline__ void gl_lds16(const ushort_t* g, ushort_t* l) {
  __builtin_amdgcn_global_load_lds(
      (const __attribute__((address_space(1))) unsigned int*)g,
      (__attribute__((address_space(3))) unsigned int*)l, 16, 0, 0);
}

// ---------------- fp32 -> bf16 conversion ----------------
__global__ void cvt_kernel(const float* __restrict__ src, ushort_t* __restrict__ dst, int n8) {
  int i = blockIdx.x * blockDim.x + threadIdx.x;
  if (i >= n8) return;
  const float4* s4 = (const float4*)src;
  float4 a = s4[2*i], b = s4[2*i+1];
  u16x8 o;
  o[0]=f2bf(a.x); o[1]=f2bf(a.y); o[2]=f2bf(a.z); o[3]=f2bf(a.w);
  o[4]=f2bf(b.x); o[5]=f2bf(b.y); o[6]=f2bf(b.z); o[7]=f2bf(b.w);
  ((u16x8*)dst)[i] = o;
}

// ---------------- QKV GEMM: qkv = x @ Wi^T + bi ----------------
// A: xb [4096][1024] bf16 row-major, B: Wib [3072][1024] bf16 row-major (out,in)
// 128x128 tile, BK=32, 4 waves (2x2), each wave 64x64 (4x4 MFMA tiles)
#define BKg 32
__global__ __launch_bounds__(256) void gemm_qkv(
    const ushort_t* __restrict__ Abf, const ushort_t* __restrict__ Bbf,
    const float* __restrict__ bias,
    ushort_t* __restrict__ qb, ushort_t* __restrict__ kb, ushort_t* __restrict__ vb) {
  __shared__ __align__(16) ushort_t Al[128*BKg];
  __shared__ __align__(16) ushort_t Bl[128*BKg];
  int tid = threadIdx.x;
  int w = tid >> 6, lane = tid & 63;
  int wrow = (w >> 1) * 64, wcol = (w & 1) * 64;
  int m0 = blockIdx.y * 128, n0 = blockIdx.x * 128;
  const int K = D_;
  f32x4 zero = {0.f, 0.f, 0.f, 0.f};
  f32x4 acc[4][4];
  for (int i=0;i<4;i++) for (int j=0;j<4;j++) acc[i][j] = zero;

  for (int k0 = 0; k0 < K; k0 += BKg) {
    __syncthreads();
    // stage A,B: 512 chunks of 16B each (128 rows x 4 chunks of 8 bf16)
    for (int it = 0; it < 2; ++it) {
      int c = it*256 + tid;
      int row = c >> 2, cc = c & 3;
      int lbase = (it*256 + w*64) * 8;  // elements
      gl_lds16(Abf + (size_t)(m0+row)*K + k0 + cc*8, Al + lbase);
      gl_lds16(Bbf + (size_t)(n0+row)*K + k0 + cc*8, Bl + lbase);
    }
    asm volatile("s_waitcnt vmcnt(0)" ::: "memory");
    __syncthreads();
    int kof = (lane >> 4) * 8;
    bf16x8 af[4], bfr[4];
    for (int i=0;i<4;i++) af[i]  = *(const bf16x8*)(Al + (wrow + i*16 + (lane&15))*BKg + kof);
    for (int j=0;j<4;j++) bfr[j] = *(const bf16x8*)(Bl + (wcol + j*16 + (lane&15))*BKg + kof);
    for (int i=0;i<4;i++)
      for (int j=0;j<4;j++)
        acc[i][j] = __builtin_amdgcn_mfma_f32_16x16x32_bf16(af[i], bfr[j], acc[i][j], 0, 0, 0);
  }
  // epilogue: scatter into q/k/v head layouts [B,H,S,DH], v same layout
  for (int i=0;i<4;i++)
    for (int j=0;j<4;j++)
      for (int r=0;r<4;r++) {
        int gm = m0 + wrow + i*16 + (lane>>4)*4 + r;
        int gn = n0 + wcol + j*16 + (lane&15);
        float v = acc[i][j][r] + bias[gn];
        int b = gm >> 11, s = gm & (S_-1);
        int sect = gn >> 10, hn = gn & (D_-1);
        int hh = hn >> 6, d = hn & 63;
        size_t idx = (((size_t)(b*H_ + hh))*S_ + s)*DH_ + d;
        ushort_t val = f2bf(v);
        if (sect == 0) qb[idx] = val;
        else if (sect == 1) kb[idx] = val;
        else vb[idx] = val;
      }
}

// ---------------- flash attention ----------------
// grid: (S/128, B*H); 4 waves, each owns 32 q-rows; KV blocks of 64
__global__ __launch_bounds__(256) void attn_fwd(
    const ushort_t* __restrict__ qb, const ushort_t* __restrict__ kb,
    const ushort_t* __restrict__ vb, ushort_t* __restrict__ attnb,
    const int* __restrict__ causal) {
  int qblk = blockIdx.x;
  int bh = blockIdx.y;
  int b = bh >> 4, h = bh & 15;
  int tid = threadIdx.x, w = tid >> 6, lane = tid & 63;
  const ushort_t* qh = qb + (size_t)bh * S_ * DH_;
  const ushort_t* kh = kb + (size_t)bh * S_ * DH_;
  const ushort_t* vh = vb + (size_t)bh * S_ * DH_;
  __shared__ __align__(16) ushort_t Kl[64*72];
  __shared__ __align__(16) ushort_t Vtl[64*72];
  __shared__ __align__(16) ushort_t Pl[4][32*72];
  int qw = qblk*128 + w*32;
  bool use_causal = (causal[0] != 0);

  bf16x8 qf[2][2];
  for (int t=0;t<2;t++)
    for (int kk=0;kk<2;kk++)
      qf[t][kk] = *(const bf16x8*)(qh + (size_t)(qw + t*16 + (lane&15))*DH_ + kk*32 + (lane>>4)*8);

  f32x4 zero = {0.f,0.f,0.f,0.f};
  f32x4 o[2][4];
  for (int t=0;t<2;t++) for (int j=0;j<4;j++) o[t][j] = zero;
  float mrun[2][4], lrun[2][4];
  for (int t=0;t<2;t++) for (int r=0;r<4;r++) { mrun[t][r] = -__builtin_inff(); lrun[t][r] = 0.f; }

  int nkv = use_causal ? (qblk*2 + 2) : (S_/64);
  for (int kv = 0; kv < nkv; ++kv) {
    int kvbase = kv*64;
    __syncthreads();
    // stage K row-major [64][72], V transposed -> Vt [64][72]
    for (int it = 0; it < 2; ++it) {
      int c = it*256 + tid;
      int row = c >> 3, cc = c & 7;
      uint4 kd = *(const uint4*)(kh + (size_t)(kvbase+row)*DH_ + cc*8);
      *(uint4*)(Kl + row*72 + cc*8) = kd;
      uint4 vd = *(const uint4*)(vh + (size_t)(kvbase+row)*DH_ + cc*8);
      const ushort_t* ve = (const ushort_t*)&vd;
      for (int e=0;e<8;e++) Vtl[(cc*8+e)*72 + row] = ve[e];
    }
    __syncthreads();
    // QK^T: S_tile(32xKVB) = Q(32x64) * K^T
    f32x4 sacc[2][4];
    for (int t=0;t<2;t++) for (int j=0;j<4;j++) sacc[t][j] = zero;
    for (int kk=0;kk<2;kk++) {
      bf16x8 kf[4];
      for (int j=0;j<4;j++)
        kf[j] = *(const bf16x8*)(Kl + (j*16 + (lane&15))*72 + kk*32 + (lane>>4)*8);
      for (int t=0;t<2;t++)
        for (int j=0;j<4;j++)
          sacc[t][j] = __builtin_amdgcn_mfma_f32_16x16x32_bf16(qf[t][kk], kf[j], sacc[t][j], 0, 0, 0);
    }
    // online softmax per q-row
    for (int t=0;t<2;t++) {
      for (int r=0;r<4;r++) {
        int qrow = qw + t*16 + (lane>>4)*4 + r;
        float sc[4];
        float mblk = -__builtin_inff();
        for (int j=0;j<4;j++) {
          int col = kvbase + j*16 + (lane&15);
          float v = sacc[t][j][r] * 0.125f;
          if (use_causal && col > qrow) v = -__builtin_inff();
          sc[j] = v;
          mblk = fmaxf(mblk, v);
        }
        for (int ms=1; ms<16; ms<<=1) mblk = fmaxf(mblk, __shfl_xor(mblk, ms, 64));
        float mnew = fmaxf(mrun[t][r], mblk);
        float alpha = __expf(mrun[t][r] - mnew);
        float rsum = 0.f;
        ushort_t pv[4];
        for (int j=0;j<4;j++) {
          float p = __expf(sc[j] - mnew);
          rsum += p;
          pv[j] = f2bf(p);
        }
        for (int ms=1; ms<16; ms<<=1) rsum += __shfl_xor(rsum, ms, 64);
        lrun[t][r] = lrun[t][r]*alpha + rsum;
        mrun[t][r] = mnew;
        for (int j2=0;j2<4;j2++) o[t][j2][r] *= alpha;
        int prow = t*16 + (lane>>4)*4 + r;
        for (int j=0;j<4;j++) Pl[w][prow*72 + j*16 + (lane&15)] = pv[j];
      }
    }
    // PV: O += P(32x64) * V(64x64), V as Vt rows (B^T pattern)
    for (int kk=0;kk<2;kk++) {
      bf16x8 pf[2], vf[4];
      for (int t=0;t<2;t++)
        pf[t] = *(const bf16x8*)(Pl[w] + (t*16 + (lane&15))*72 + kk*32 + (lane>>4)*8);
      for (int dt=0;dt<4;dt++)
        vf[dt] = *(const bf16x8*)(Vtl + (dt*16 + (lane&15))*72 + kk*32 + (lane>>4)*8);
      for (int t=0;t<2;t++)
        for (int dt=0;dt<4;dt++)
          o[t][dt] = __builtin_amdgcn_mfma_f32_16x16x32_bf16(pf[t], vf[dt], o[t][dt], 0, 0, 0);
    }
  }
  // write attn output [B,S,D] bf16: attn[(b*S+q)*D + h*64 + d]
  for (int t=0;t<2;t++)
    for (int r=0;r<4;r++) {
      float linv = 1.f / lrun[t][r];
      int q = qw + t*16 + (lane>>4)*4 + r;
      for (int dt=0;dt<4;dt++) {
        int d = dt*16 + (lane&15);
        attnb[((size_t)(b*S_ + q))*D_ + h*DH_ + d] = f2bf(o[t][dt][r] * linv);
      }
    }
}

// ---------------- output GEMM: out = attn @ Wo^T + bo (fp32 out) ----------------
__global__ __launch_bounds__(256) void gemm_out(
    const ushort_t* __restrict__ Abf, const ushort_t* __restrict__ Bbf,
    const float* __restrict__ bias, float* __restrict__ out) {
  __shared__ __align__(16) ushort_t Al[128*BKg];
  __shared__ __align__(16) ushort_t Bl[128*BKg];
  int tid = threadIdx.x;
  int w = tid >> 6, lane = tid & 63;
  int wrow = (w >> 1) * 64, wcol = (w & 1) * 64;
  int m0 = blockIdx.y * 128, n0 = blockIdx.x * 128;
  const int K = D_;
  f32x4 zero = {0.f,0.f,0.f,0.f};
  f32x4 acc[4][4];
  for (int i=0;i<4;i++) for (int j=0;j<4;j++) acc[i][j] = zero;

  for (int k0 = 0; k0 < K; k0 += BKg) {
    __syncthreads();
    for (int it = 0; it < 2; ++it) {
      int c = it*256 + tid;
      int row = c >> 2, cc = c & 3;
      int lbase = (it*256 + w*64) * 8;
      gl_lds16(Abf + (size_t)(m0+row)*K + k0 + cc*8, Al + lbase);
      gl_lds16(Bbf + (size_t)(n0+row)*K + k0 + cc*8, Bl + lbase);
    }
    asm volatile("s_waitcnt vmcnt(0)" ::: "memory");
    __syncthreads();
    int kof = (lane >> 4) * 8;
    bf16x8 af[4], bfr[4];
    for (int i=0;i<4;i++) af[i]  = *(const bf16x8*)(Al + (wrow + i*16 + (lane&15))*BKg + kof);
    for (int j=0;j<4;j++) bfr[j] = *(const bf16x8*)(Bl + (wcol + j*16 + (lane&15))*BKg + kof);
    for (int i=0;i<4;i++)
      for (int j=0;j<4;j++)
        acc[i][j] = __builtin_amdgcn_mfma_f32_16x16x32_bf16(af[i], bfr[j], acc[i][j], 0, 0, 0);
  }
  for (int i=0;i<4;i++)
    for (int j=0;j<4;j++)
      for (int r=0;r<4;r++) {
        int gm = m0 + wrow + i*16 + (lane>>4)*4 + r;
        int gn = n0 + wcol + j*16 + (lane&15);
        out[(size_t)gm*D_ + gn] = acc[i][j][r] + bias[gn];
      }
}

extern "C" void kernel_launch(void* const* d_in, const int* in_sizes, int n_in,
                              void* d_out, int out_size, void* d_ws, size_t ws_size,
                              hipStream_t stream) {
  const float* x  = (const float*)d_in[0];
  const float* Wi = (const float*)d_in[1];
  const float* bi = (const float*)d_in[2];
  const float* Wo = (const float*)d_in[3];
  const float* bo = (const float*)d_in[4];
  const int* causal = (const int*)d_in[5];
  float* out = (float*)d_out;

  ushort_t* xb   = (ushort_t*)d_ws;                       // 4096*1024
  ushort_t* Wib  = xb  + (size_t)MTOT*D_;                 // 3072*1024
  ushort_t* Wob  = Wib + (size_t)NQKV*D_;                 // 1024*1024
  ushort_t* qbuf = Wob + (size_t)D_*D_;                   // 4096*64*16
  ushort_t* kbuf = qbuf + (size_t)B_*H_*S_*DH_;
  ushort_t* vbuf = kbuf + (size_t)B_*H_*S_*DH_;
  ushort_t* attnb = vbuf + (size_t)B_*H_*S_*DH_;          // 4096*1024

  int n1 = MTOT*D_/8;
  cvt_kernel<<<(n1+255)/256, 256, 0, stream>>>(x, xb, n1);
  int n2 = NQKV*D_/8;
  cvt_kernel<<<(n2+255)/256, 256, 0, stream>>>(Wi, Wib, n2);
  int n3 = D_*D_/8;
  cvt_kernel<<<(n3+255)/256, 256, 0, stream>>>(Wo, Wob, n3);

  gemm_qkv<<<dim3(NQKV/128, MTOT/128), 256, 0, stream>>>(xb, Wib, bi, qbuf, kbuf, vbuf);
  attn_fwd<<<dim3(S_/128, B_*H_), 256, 0, stream>>>(qbuf, kbuf, vbuf, attnb, causal);
  gemm_out<<<dim3(D_/128, MTOT/128), 256, 0, stream>>>(attnb, Wob, bo, out);
}

// Round 2
// 181.685 us; speedup vs baseline: 1.3058x; 1.3058x over previous
//
#include <hip/hip_runtime.h>
#include <hip/hip_bf16.h>
#include <stdint.h>

#define B_    2
#define S_    2048
#define D_    1024
#define H_    16
#define DH_   64
#define MTOT  (B_*S_)     // 4096
#define NQKV  (3*D_)      // 3072

typedef __attribute__((ext_vector_type(8))) short  bf16x8;
typedef __attribute__((ext_vector_type(4))) float  f32x4;
typedef __attribute__((ext_vector_type(8))) unsigned short u16x8;
typedef unsigned short ushort_t;

__device__ __forceinline__ ushort_t f2bf(float f) {
  union { float f; unsigned int i; } v; v.f = f;
  unsigned int r = v.i + 0x7FFF + ((v.i >> 16) & 1);
  return (ushort_t)(r >> 16);
}

__device__ __forceinline__ void gl_lds16(const ushort_t* g, ushort_t* l) {
  __builtin_amdgcn_global_load_lds(
      (const __attribute__((address_space(1))) unsigned int*)g,
      (__attribute__((address_space(3))) unsigned int*)l, 16, 0, 0);
}

// ---------------- fp32 -> bf16 conversion ----------------
__global__ void cvt_kernel(const float* __restrict__ src, ushort_t* __restrict__ dst, int n8) {
  int i = blockIdx.x * blockDim.x + threadIdx.x;
  if (i >= n8) return;
  const float4* s4 = (const float4*)src;
  float4 a = s4[2*i], b = s4[2*i+1];
  u16x8 o;
  o[0]=f2bf(a.x); o[1]=f2bf(a.y); o[2]=f2bf(a.z); o[3]=f2bf(a.w);
  o[4]=f2bf(b.x); o[5]=f2bf(b.y); o[6]=f2bf(b.z); o[7]=f2bf(b.w);
  ((u16x8*)dst)[i] = o;
}

// ---------------- QKV GEMM: qkv = x @ Wi^T + bi ----------------
#define BKg 32
__global__ __launch_bounds__(256) void gemm_qkv(
    const ushort_t* __restrict__ Abf, const ushort_t* __restrict__ Bbf,
    const float* __restrict__ bias,
    ushort_t* __restrict__ qb, ushort_t* __restrict__ kb, ushort_t* __restrict__ vb) {
  __shared__ __align__(16) ushort_t Al[128*BKg];
  __shared__ __align__(16) ushort_t Bl[128*BKg];
  int tid = threadIdx.x;
  int w = tid >> 6, lane = tid & 63;
  int wrow = (w >> 1) * 64, wcol = (w & 1) * 64;
  int m0 = blockIdx.y * 128, n0 = blockIdx.x * 128;
  const int K = D_;
  f32x4 zero = {0.f, 0.f, 0.f, 0.f};
  f32x4 acc[4][4];
  for (int i=0;i<4;i++) for (int j=0;j<4;j++) acc[i][j] = zero;

  for (int k0 = 0; k0 < K; k0 += BKg) {
    __syncthreads();
    for (int it = 0; it < 2; ++it) {
      int c = it*256 + tid;
      int row = c >> 2, cc = c & 3;
      int lbase = (it*256 + w*64) * 8;
      gl_lds16(Abf + (size_t)(m0+row)*K + k0 + cc*8, Al + lbase);
      gl_lds16(Bbf + (size_t)(n0+row)*K + k0 + cc*8, Bl + lbase);
    }
    asm volatile("s_waitcnt vmcnt(0)" ::: "memory");
    __syncthreads();
    int kof = (lane >> 4) * 8;
    bf16x8 af[4], bfr[4];
    for (int i=0;i<4;i++) af[i]  = *(const bf16x8*)(Al + (wrow + i*16 + (lane&15))*BKg + kof);
    for (int j=0;j<4;j++) bfr[j] = *(const bf16x8*)(Bl + (wcol + j*16 + (lane&15))*BKg + kof);
    for (int i=0;i<4;i++)
      for (int j=0;j<4;j++)
        acc[i][j] = __builtin_amdgcn_mfma_f32_16x16x32_bf16(af[i], bfr[j], acc[i][j], 0, 0, 0);
  }
  for (int i=0;i<4;i++)
    for (int j=0;j<4;j++)
      for (int r=0;r<4;r++) {
        int gm = m0 + wrow + i*16 + (lane>>4)*4 + r;
        int gn = n0 + wcol + j*16 + (lane&15);
        float v = acc[i][j][r] + bias[gn];
        int b = gm >> 11, s = gm & (S_-1);
        int sect = gn >> 10, hn = gn & (D_-1);
        int hh = hn >> 6, d = hn & 63;
        size_t idx = (((size_t)(b*H_ + hh))*S_ + s)*DH_ + d;
        ushort_t val = f2bf(v);
        if (sect == 0) qb[idx] = val;
        else if (sect == 1) kb[idx] = val;
        else vb[idx] = val;
      }
}

// ---------------- V transpose: [BH][S][DH] -> [BH][DH][S] ----------------
__global__ __launch_bounds__(256) void transpose_v(
    const ushort_t* __restrict__ vb, ushort_t* __restrict__ vtb) {
  __shared__ ushort_t T[64*72];
  int bh = blockIdx.y;
  int s0 = blockIdx.x * 64;
  int tid = threadIdx.x;
  const ushort_t* src = vb + (size_t)bh * S_ * DH_;
  ushort_t* dst = vtb + (size_t)bh * DH_ * S_;
  for (int it = 0; it < 2; ++it) {
    int c = it*256 + tid;
    int row = c >> 3, cc = c & 7;
    *(uint4*)&T[row*72 + cc*8] = *(const uint4*)(src + (size_t)(s0+row)*DH_ + cc*8);
  }
  __syncthreads();
  for (int it = 0; it < 2; ++it) {
    int c = it*256 + tid;
    int d = c >> 3, sc = c & 7;
    u16x8 o;
    #pragma unroll
    for (int e = 0; e < 8; ++e) o[e] = T[(sc*8+e)*72 + d];
    *(u16x8*)(dst + (size_t)d*S_ + s0 + sc*8) = o;
  }
}

// ---------------- flash attention v2 ----------------
// grid: (S/128, B*H); 8 waves x 16 q-rows; KV blocks of 64, double-buffered,
// K and Vt staged via global_load_lds with XOR chunk-swizzle (src-side + read-side).
#define KVB 64
__global__ __launch_bounds__(512) void attn_fwd(
    const ushort_t* __restrict__ qb, const ushort_t* __restrict__ kb,
    const ushort_t* __restrict__ vtb, ushort_t* __restrict__ attnb,
    const int* __restrict__ causal) {
  int qblk = (gridDim.x - 1) - blockIdx.x;   // long causal blocks first
  int bh = blockIdx.y;
  int b = bh >> 4, h = bh & 15;
  int tid = threadIdx.x, w = tid >> 6, lane = tid & 63;
  const ushort_t* qh  = qb  + (size_t)bh * S_ * DH_;
  const ushort_t* kh  = kb  + (size_t)bh * S_ * DH_;
  const ushort_t* vth = vtb + (size_t)bh * DH_ * S_;
  __shared__ __align__(16) ushort_t Kl[2][KVB*64];    // [s][d-chunk swizzled]
  __shared__ __align__(16) ushort_t Vtl[2][64*KVB];   // [d][s-chunk swizzled]
  __shared__ __align__(16) ushort_t Pl[8][16*72];
  int qw = qblk*128 + w*16;
  bool use_causal = (causal[0] != 0);

  // Q fragments: row = lane&15, k = kk*32 + (lane>>4)*8
  bf16x8 qf[2];
  #pragma unroll
  for (int kk=0; kk<2; kk++)
    qf[kk] = *(const bf16x8*)(qh + (size_t)(qw + (lane&15))*DH_ + kk*32 + (lane>>4)*8);

  f32x4 zero = {0.f,0.f,0.f,0.f};
  f32x4 o[4];
  #pragma unroll
  for (int j=0;j<4;j++) o[j] = zero;
  float mrun[4], lrun[4];
  #pragma unroll
  for (int r=0;r<4;r++) { mrun[r] = -__builtin_inff(); lrun[r] = 0.f; }

  // staging: thread -> one 16B K chunk + one 16B Vt chunk; LDS linear, source swizzled
  int srow = tid >> 3, scc = tid & 7;
  int ssrc = (scc ^ (srow & 7)) * 8;
  const ushort_t* ksrc0 = kh + (size_t)srow * DH_ + ssrc;
  const ushort_t* vsrc0 = vth + (size_t)srow * S_ + ssrc;

  int nkv = use_causal ? (qblk*2 + 2) : (S_/KVB);

  // prologue: stage kv=0 into buf 0
  gl_lds16(ksrc0, &Kl[0][tid*8]);
  gl_lds16(vsrc0 + 0, &Vtl[0][tid*8]);
  asm volatile("s_waitcnt vmcnt(0)" ::: "memory");
  __syncthreads();

  for (int kv = 0; kv < nkv; ++kv) {
    int cur = kv & 1;
    int kvbase = kv * KVB;
    if (kv + 1 < nkv) {
      // stage next tile into other buffer (overlaps with compute below)
      gl_lds16(ksrc0 + (size_t)(kvbase + KVB) * DH_, &Kl[cur^1][tid*8]);
      gl_lds16(vsrc0 + kvbase + KVB, &Vtl[cur^1][tid*8]);
    }
    // ---- QK^T: S(16xKVB) = Q(16x64) K^T ----
    f32x4 sacc[4];
    #pragma unroll
    for (int j=0;j<4;j++) sacc[j] = zero;
    #pragma unroll
    for (int kk=0;kk<2;kk++) {
      #pragma unroll
      for (int j=0;j<4;j++) {
        int row = j*16 + (lane&15);
        int slot = (kk*4 + (lane>>4)) ^ (lane & 7);
        bf16x8 kf = *(const bf16x8*)(&Kl[cur][row*64 + slot*8]);
        sacc[j] = __builtin_amdgcn_mfma_f32_16x16x32_bf16(qf[kk], kf, sacc[j], 0, 0, 0);
      }
    }
    // ---- online softmax (4 rows/thread) ----
    #pragma unroll
    for (int r=0;r<4;r++) {
      int qrow = qw + (lane>>4)*4 + r;
      float sc[4];
      float mblk = -__builtin_inff();
      #pragma unroll
      for (int j=0;j<4;j++) {
        int col = kvbase + j*16 + (lane&15);
        float v = sacc[j][r] * 0.125f;
        if (use_causal && col > qrow) v = -__builtin_inff();
        sc[j] = v;
        mblk = fmaxf(mblk, v);
      }
      #pragma unroll
      for (int ms=1; ms<16; ms<<=1) mblk = fmaxf(mblk, __shfl_xor(mblk, ms, 64));
      float mnew = fmaxf(mrun[r], mblk);
      float alpha = __expf(mrun[r] - mnew);
      float rsum = 0.f;
      int prow = (lane>>4)*4 + r;
      #pragma unroll
      for (int j=0;j<4;j++) {
        float p = __expf(sc[j] - mnew);
        rsum += p;
        Pl[w][prow*72 + j*16 + (lane&15)] = f2bf(p);
      }
      #pragma unroll
      for (int ms=1; ms<16; ms<<=1) rsum += __shfl_xor(rsum, ms, 64);
      lrun[r] = lrun[r]*alpha + rsum;
      mrun[r] = mnew;
      #pragma unroll
      for (int dt=0;dt<4;dt++) o[dt][r] *= alpha;
    }
    // ---- PV: O += P(16xKVB) V(KVBx64), V from Vt rows (B^T pattern) ----
    #pragma unroll
    for (int kk=0;kk<2;kk++) {
      bf16x8 pf = *(const bf16x8*)(&Pl[w][(lane&15)*72 + kk*32 + (lane>>4)*8]);
      #pragma unroll
      for (int dt=0;dt<4;dt++) {
        int row = dt*16 + (lane&15);
        int slot = (kk*4 + (lane>>4)) ^ (lane & 7);
        bf16x8 vf = *(const bf16x8*)(&Vtl[cur][row*64 + slot*8]);
        o[dt] = __builtin_amdgcn_mfma_f32_16x16x32_bf16(pf, vf, o[dt], 0, 0, 0);
      }
    }
    asm volatile("s_waitcnt vmcnt(0)" ::: "memory");
    __syncthreads();
  }
  // ---- epilogue ----
  #pragma unroll
  for (int r=0;r<4;r++) {
    float linv = 1.f / lrun[r];
    int q = qw + (lane>>4)*4 + r;
    #pragma unroll
    for (int dt=0;dt<4;dt++) {
      int d = dt*16 + (lane&15);
      attnb[((size_t)(b*S_ + q))*D_ + h*DH_ + d] = f2bf(o[dt][r] * linv);
    }
  }
}

// ---------------- output GEMM: out = attn @ Wo^T + bo (fp32 out) ----------------
__global__ __launch_bounds__(256) void gemm_out(
    const ushort_t* __restrict__ Abf, const ushort_t* __restrict__ Bbf,
    const float* __restrict__ bias, float* __restrict__ out) {
  __shared__ __align__(16) ushort_t Al[128*BKg];
  __shared__ __align__(16) ushort_t Bl[128*BKg];
  int tid = threadIdx.x;
  int w = tid >> 6, lane = tid & 63;
  int wrow = (w >> 1) * 64, wcol = (w & 1) * 64;
  int m0 = blockIdx.y * 128, n0 = blockIdx.x * 128;
  const int K = D_;
  f32x4 zero = {0.f,0.f,0.f,0.f};
  f32x4 acc[4][4];
  for (int i=0;i<4;i++) for (int j=0;j<4;j++) acc[i][j] = zero;

  for (int k0 = 0; k0 < K; k0 += BKg) {
    __syncthreads();
    for (int it = 0; it < 2; ++it) {
      int c = it*256 + tid;
      int row = c >> 2, cc = c & 3;
      int lbase = (it*256 + w*64) * 8;
      gl_lds16(Abf + (size_t)(m0+row)*K + k0 + cc*8, Al + lbase);
      gl_lds16(Bbf + (size_t)(n0+row)*K + k0 + cc*8, Bl + lbase);
    }
    asm volatile("s_waitcnt vmcnt(0)" ::: "memory");
    __syncthreads();
    int kof = (lane >> 4) * 8;
    bf16x8 af[4], bfr[4];
    for (int i=0;i<4;i++) af[i]  = *(const bf16x8*)(Al + (wrow + i*16 + (lane&15))*BKg + kof);
    for (int j=0;j<4;j++) bfr[j] = *(const bf16x8*)(Bl + (wcol + j*16 + (lane&15))*BKg + kof);
    for (int i=0;i<4;i++)
      for (int j=0;j<4;j++)
        acc[i][j] = __builtin_amdgcn_mfma_f32_16x16x32_bf16(af[i], bfr[j], acc[i][j], 0, 0, 0);
  }
  for (int i=0;i<4;i++)
    for (int j=0;j<4;j++)
      for (int r=0;r<4;r++) {
        int gm = m0 + wrow + i*16 + (lane>>4)*4 + r;
        int gn = n0 + wcol + j*16 + (lane&15);
        out[(size_t)gm*D_ + gn] = acc[i][j][r] + bias[gn];
      }
}

extern "C" void kernel_launch(void* const* d_in, const int* in_sizes, int n_in,
                              void* d_out, int out_size, void* d_ws, size_t ws_size,
                              hipStream_t stream) {
  const float* x  = (const float*)d_in[0];
  const float* Wi = (const float*)d_in[1];
  const float* bi = (const float*)d_in[2];
  const float* Wo = (const float*)d_in[3];
  const float* bo = (const float*)d_in[4];
  const int* causal = (const int*)d_in[5];
  float* out = (float*)d_out;

  ushort_t* xb   = (ushort_t*)d_ws;                       // 4096*1024 (reused as vtb)
  ushort_t* Wib  = xb  + (size_t)MTOT*D_;                 // 3072*1024
  ushort_t* Wob  = Wib + (size_t)NQKV*D_;                 // 1024*1024
  ushort_t* qbuf = Wob + (size_t)D_*D_;                   // 32*2048*64
  ushort_t* kbuf = qbuf + (size_t)B_*H_*S_*DH_;
  ushort_t* vbuf = kbuf + (size_t)B_*H_*S_*DH_;
  ushort_t* attnb = vbuf + (size_t)B_*H_*S_*DH_;          // 4096*1024
  ushort_t* vtb  = xb;  // xb is dead after gemm_qkv; reuse for transposed V

  int n1 = MTOT*D_/8;
  cvt_kernel<<<(n1+255)/256, 256, 0, stream>>>(x, xb, n1);
  int n2 = NQKV*D_/8;
  cvt_kernel<<<(n2+255)/256, 256, 0, stream>>>(Wi, Wib, n2);
  int n3 = D_*D_/8;
  cvt_kernel<<<(n3+255)/256, 256, 0, stream>>>(Wo, Wob, n3);

  gemm_qkv<<<dim3(NQKV/128, MTOT/128), 256, 0, stream>>>(xb, Wib, bi, qbuf, kbuf, vbuf);
  transpose_v<<<dim3(S_/64, B_*H_), 256, 0, stream>>>(vbuf, vtb);
  attn_fwd<<<dim3(S_/128, B_*H_), 512, 0, stream>>>(qbuf, kbuf, vtb, attnb, causal);
  gemm_out<<<dim3(D_/128, MTOT/128), 256, 0, stream>>>(attnb, Wob, bo, out);
}

// Round 3
// 133.785 us; speedup vs baseline: 1.7734x; 1.3580x over previous
//
#include <hip/hip_runtime.h>
#include <hip/hip_bf16.h>
#include <stdint.h>

#define B_    2
#define S_    2048
#define D_    1024
#define H_    16
#define DH_   64
#define MTOT  (B_*S_)     // 4096
#define NQKV  (3*D_)      // 3072

typedef __attribute__((ext_vector_type(8))) short  bf16x8;
typedef __attribute__((ext_vector_type(4))) float  f32x4;
typedef __attribute__((ext_vector_type(8))) unsigned short u16x8;
typedef unsigned short ushort_t;

__device__ __forceinline__ ushort_t f2bf(float f) {
  union { float f; unsigned int i; } v; v.f = f;
  unsigned int r = v.i + 0x7FFF + ((v.i >> 16) & 1);
  return (ushort_t)(r >> 16);
}

__device__ __forceinline__ unsigned cvt_pk_bf16(float lo, float hi) {
  unsigned r;
  asm("v_cvt_pk_bf16_f32 %0, %1, %2" : "=v"(r) : "v"(lo), "v"(hi));
  return r;
}

__device__ __forceinline__ void gl_lds16(const ushort_t* g, ushort_t* l) {
  __builtin_amdgcn_global_load_lds(
      (const __attribute__((address_space(1))) unsigned int*)g,
      (__attribute__((address_space(3))) unsigned int*)l, 16, 0, 0);
}

// ---------------- fp32 -> bf16 conversion ----------------
__global__ void cvt_kernel(const float* __restrict__ src, ushort_t* __restrict__ dst, int n8) {
  int i = blockIdx.x * blockDim.x + threadIdx.x;
  if (i >= n8) return;
  const float4* s4 = (const float4*)src;
  float4 a = s4[2*i], b = s4[2*i+1];
  u16x8 o;
  o[0]=f2bf(a.x); o[1]=f2bf(a.y); o[2]=f2bf(a.z); o[3]=f2bf(a.w);
  o[4]=f2bf(b.x); o[5]=f2bf(b.y); o[6]=f2bf(b.z); o[7]=f2bf(b.w);
  ((u16x8*)dst)[i] = o;
}

// ---------------- QKV GEMM: qkv = x @ Wi^T + bi ----------------
#define BKg 32
__global__ __launch_bounds__(256) void gemm_qkv(
    const ushort_t* __restrict__ Abf, const ushort_t* __restrict__ Bbf,
    const float* __restrict__ bias,
    ushort_t* __restrict__ qb, ushort_t* __restrict__ kb, ushort_t* __restrict__ vb) {
  __shared__ __align__(16) ushort_t Al[128*BKg];
  __shared__ __align__(16) ushort_t Bl[128*BKg];
  int tid = threadIdx.x;
  int w = tid >> 6, lane = tid & 63;
  int wrow = (w >> 1) * 64, wcol = (w & 1) * 64;
  int m0 = blockIdx.y * 128, n0 = blockIdx.x * 128;
  const int K = D_;
  f32x4 zero = {0.f, 0.f, 0.f, 0.f};
  f32x4 acc[4][4];
  for (int i=0;i<4;i++) for (int j=0;j<4;j++) acc[i][j] = zero;

  for (int k0 = 0; k0 < K; k0 += BKg) {
    __syncthreads();
    for (int it = 0; it < 2; ++it) {
      int c = it*256 + tid;
      int row = c >> 2, cc = c & 3;
      int lbase = (it*256 + w*64) * 8;
      gl_lds16(Abf + (size_t)(m0+row)*K + k0 + cc*8, Al + lbase);
      gl_lds16(Bbf + (size_t)(n0+row)*K + k0 + cc*8, Bl + lbase);
    }
    asm volatile("s_waitcnt vmcnt(0)" ::: "memory");
    __syncthreads();
    int kof = (lane >> 4) * 8;
    bf16x8 af[4], bfr[4];
    for (int i=0;i<4;i++) af[i]  = *(const bf16x8*)(Al + (wrow + i*16 + (lane&15))*BKg + kof);
    for (int j=0;j<4;j++) bfr[j] = *(const bf16x8*)(Bl + (wcol + j*16 + (lane&15))*BKg + kof);
    for (int i=0;i<4;i++)
      for (int j=0;j<4;j++)
        acc[i][j] = __builtin_amdgcn_mfma_f32_16x16x32_bf16(af[i], bfr[j], acc[i][j], 0, 0, 0);
  }
  for (int i=0;i<4;i++)
    for (int j=0;j<4;j++)
      for (int r=0;r<4;r++) {
        int gm = m0 + wrow + i*16 + (lane>>4)*4 + r;
        int gn = n0 + wcol + j*16 + (lane&15);
        float v = acc[i][j][r] + bias[gn];
        int b = gm >> 11, s = gm & (S_-1);
        int sect = gn >> 10, hn = gn & (D_-1);
        int hh = hn >> 6, d = hn & 63;
        size_t idx = (((size_t)(b*H_ + hh))*S_ + s)*DH_ + d;
        if (sect == 0) v *= 0.125f;   // fold 1/sqrt(DH) into q (exact, pow2)
        ushort_t val = f2bf(v);
        if (sect == 0) qb[idx] = val;
        else if (sect == 1) kb[idx] = val;
        else vb[idx] = val;
      }
}

// ---------------- V transpose: [BH][S][DH] -> [BH][DH][S] ----------------
__global__ __launch_bounds__(256) void transpose_v(
    const ushort_t* __restrict__ vb, ushort_t* __restrict__ vtb) {
  __shared__ ushort_t T[64*72];
  int bh = blockIdx.y;
  int s0 = blockIdx.x * 64;
  int tid = threadIdx.x;
  const ushort_t* src = vb + (size_t)bh * S_ * DH_;
  ushort_t* dst = vtb + (size_t)bh * DH_ * S_;
  for (int it = 0; it < 2; ++it) {
    int c = it*256 + tid;
    int row = c >> 3, cc = c & 7;
    *(uint4*)&T[row*72 + cc*8] = *(const uint4*)(src + (size_t)(s0+row)*DH_ + cc*8);
  }
  __syncthreads();
  for (int it = 0; it < 2; ++it) {
    int c = it*256 + tid;
    int d = c >> 3, sc = c & 7;
    u16x8 o;
    #pragma unroll
    for (int e = 0; e < 8; ++e) o[e] = T[(sc*8+e)*72 + d];
    *(u16x8*)(dst + (size_t)d*S_ + s0 + sc*8) = o;
  }
}

// ---------------- flash attention v3: swapped QK^T, paired panels ----------------
// grid (16 pairs, 32 bh), 4 waves x 16 q-rows = 64-row panels; pair (p, 31-p)
// gives every block exactly 33 causal KV iters.
#define KVB 64
__global__ __launch_bounds__(256) void attn_fwd(
    const ushort_t* __restrict__ qb, const ushort_t* __restrict__ kb,
    const ushort_t* __restrict__ vtb, ushort_t* __restrict__ attnb,
    const int* __restrict__ causal) {
  int pairIdx = blockIdx.x;  // 0..15
  int bh = blockIdx.y;
  int b = bh >> 4, h = bh & 15;
  int tid = threadIdx.x, w = tid >> 6, lane = tid & 63;
  int g = lane >> 4, q16 = lane & 15;
  const ushort_t* qh  = qb  + (size_t)bh * S_ * DH_;
  const ushort_t* kh  = kb  + (size_t)bh * S_ * DH_;
  const ushort_t* vth = vtb + (size_t)bh * DH_ * S_;
  __shared__ __align__(16) ushort_t Kl[2][KVB*64];
  __shared__ __align__(16) ushort_t Vtl[2][64*KVB];
  __shared__ __align__(16) ushort_t Pl[4][16*72];
  bool use_causal = (causal[0] != 0);

  // staging: thread covers chunks c0=tid, c1=tid+256 of both K and Vt tiles
  int c0 = tid, c1 = tid + 256;
  int r0 = c0 >> 3, sw0 = ((c0 & 7) ^ (r0 & 7)) * 8;
  int r1 = c1 >> 3, sw1 = ((c1 & 7) ^ (r1 & 7)) * 8;
  const ushort_t* kp0 = kh + r0*DH_ + sw0;
  const ushort_t* kp1 = kh + r1*DH_ + sw1;
  const ushort_t* vp0 = vth + (size_t)r0*S_ + sw0;
  const ushort_t* vp1 = vth + (size_t)r1*S_ + sw1;

  int panels[2] = { pairIdx, 31 - pairIdx };

  for (int ph = 0; ph < 2; ++ph) {
    int panel = panels[ph];
    int nkv = use_causal ? (panel + 1) : (S_ / KVB);
    int qw = panel*64 + w*16;

    bf16x8 qf[2];
    #pragma unroll
    for (int kk = 0; kk < 2; ++kk)
      qf[kk] = *(const bf16x8*)(qh + (size_t)(qw + q16)*DH_ + kk*32 + g*8);

    f32x4 zero = {0.f,0.f,0.f,0.f};
    f32x4 o[4];
    #pragma unroll
    for (int dt=0;dt<4;dt++) o[dt] = zero;
    float mrun = -1e30f, lrun = 0.f;

    // prologue: stage tile 0 into buf 0
    gl_lds16(kp0, &Kl[0][c0*8]);  gl_lds16(kp1, &Kl[0][c1*8]);
    gl_lds16(vp0, &Vtl[0][c0*8]); gl_lds16(vp1, &Vtl[0][c1*8]);
    asm volatile("s_waitcnt vmcnt(0)" ::: "memory");
    __syncthreads();

    for (int t = 0; t < nkv; ++t) {
      int cur = t & 1;
      int kvbase = t * KVB;
      if (t + 1 < nkv) {
        int nb = cur ^ 1;
        int adv = kvbase + KVB;
        gl_lds16(kp0 + (size_t)adv*DH_, &Kl[nb][c0*8]);
        gl_lds16(kp1 + (size_t)adv*DH_, &Kl[nb][c1*8]);
        gl_lds16(vp0 + adv, &Vtl[nb][c0*8]);
        gl_lds16(vp1 + adv, &Vtl[nb][c1*8]);
      }
      // ---- QK^T swapped: sacc[j] C-layout col=q16(q), row=4g+r(kv) ----
      f32x4 sacc[4];
      #pragma unroll
      for (int j=0;j<4;j++) sacc[j] = zero;
      #pragma unroll
      for (int kk=0;kk<2;kk++) {
        #pragma unroll
        for (int j=0;j<4;j++) {
          int row = j*16 + q16;
          int slot = (kk*4 + g) ^ (row & 7);
          bf16x8 kf = *(const bf16x8*)(&Kl[cur][row*64 + slot*8]);
          sacc[j] = __builtin_amdgcn_mfma_f32_16x16x32_bf16(kf, qf[kk], sacc[j], 0, 0, 0);
        }
      }
      // ---- softmax, fully in-register (one q per lane, 16 kv per lane) ----
      float sc[4][4];
      if (use_causal && t == nkv-1) {
        int qrel = 16*w + q16;
        #pragma unroll
        for (int j=0;j<4;j++)
          #pragma unroll
          for (int r=0;r<4;r++)
            sc[j][r] = (16*j + 4*g + r > qrel) ? -1e30f : sacc[j][r];
      } else {
        #pragma unroll
        for (int j=0;j<4;j++)
          #pragma unroll
          for (int r=0;r<4;r++)
            sc[j][r] = sacc[j][r];
      }
      float m01 = fmaxf(fmaxf(sc[0][0], sc[0][1]), fmaxf(sc[0][2], sc[0][3]));
      float m11 = fmaxf(fmaxf(sc[1][0], sc[1][1]), fmaxf(sc[1][2], sc[1][3]));
      float m21 = fmaxf(fmaxf(sc[2][0], sc[2][1]), fmaxf(sc[2][2], sc[2][3]));
      float m31 = fmaxf(fmaxf(sc[3][0], sc[3][1]), fmaxf(sc[3][2], sc[3][3]));
      float mx = fmaxf(fmaxf(m01, m11), fmaxf(m21, m31));
      mx = fmaxf(mx, __shfl_xor(mx, 16, 64));
      mx = fmaxf(mx, __shfl_xor(mx, 32, 64));
      float mnew = fmaxf(mrun, mx);
      float alpha = __expf(mrun - mnew);
      float p[4][4];
      float rs = 0.f;
      #pragma unroll
      for (int j=0;j<4;j++) {
        #pragma unroll
        for (int r=0;r<4;r++) {
          p[j][r] = __expf(sc[j][r] - mnew);
          rs += p[j][r];
        }
      }
      rs += __shfl_xor(rs, 16, 64);
      rs += __shfl_xor(rs, 32, 64);
      lrun = lrun*alpha + rs;
      mrun = mnew;
      // ---- pack P into Pl[w]: row=q16, kv offset 16j+4g ----
      #pragma unroll
      for (int j=0;j<4;j++) {
        uint2 pw;
        pw.x = cvt_pk_bf16(p[j][0], p[j][1]);
        pw.y = cvt_pk_bf16(p[j][2], p[j][3]);
        *(uint2*)&Pl[w][q16*72 + j*16 + g*4] = pw;
      }
      // ---- rescale O (rows q=4g+r) ----
      float av0 = __shfl(alpha, 4*g + 0, 64);
      float av1 = __shfl(alpha, 4*g + 1, 64);
      float av2 = __shfl(alpha, 4*g + 2, 64);
      float av3 = __shfl(alpha, 4*g + 3, 64);
      #pragma unroll
      for (int dt=0;dt<4;dt++) {
        o[dt][0] *= av0; o[dt][1] *= av1; o[dt][2] *= av2; o[dt][3] *= av3;
      }
      // ---- PV: O += P(16x64) V(64x64) ----
      #pragma unroll
      for (int kk=0;kk<2;kk++) {
        bf16x8 pf = *(const bf16x8*)&Pl[w][q16*72 + kk*32 + g*8];
        #pragma unroll
        for (int dt=0;dt<4;dt++) {
          int row = dt*16 + q16;
          int slot = (kk*4 + g) ^ (row & 7);
          bf16x8 vf = *(const bf16x8*)(&Vtl[cur][row*64 + slot*8]);
          o[dt] = __builtin_amdgcn_mfma_f32_16x16x32_bf16(pf, vf, o[dt], 0, 0, 0);
        }
      }
      asm volatile("s_waitcnt vmcnt(0)" ::: "memory");
      __syncthreads();
    }
    // ---- epilogue: O rows q=4g+r, cols d=dt*16+q16 ----
    float li0 = 1.f / __shfl(lrun, 4*g + 0, 64);
    float li1 = 1.f / __shfl(lrun, 4*g + 1, 64);
    float li2 = 1.f / __shfl(lrun, 4*g + 2, 64);
    float li3 = 1.f / __shfl(lrun, 4*g + 3, 64);
    #pragma unroll
    for (int r=0;r<4;r++) {
      float li = (r==0)?li0:(r==1)?li1:(r==2)?li2:li3;
      int q = qw + 4*g + r;
      #pragma unroll
      for (int dt=0;dt<4;dt++) {
        int d = dt*16 + q16;
        attnb[((size_t)(b*S_ + q))*D_ + h*DH_ + d] = f2bf(o[dt][r] * li);
      }
    }
  }
}

// ---------------- output GEMM: out = attn @ Wo^T + bo (fp32 out) ----------------
__global__ __launch_bounds__(256) void gemm_out(
    const ushort_t* __restrict__ Abf, const ushort_t* __restrict__ Bbf,
    const float* __restrict__ bias, float* __restrict__ out) {
  __shared__ __align__(16) ushort_t Al[128*BKg];
  __shared__ __align__(16) ushort_t Bl[128*BKg];
  int tid = threadIdx.x;
  int w = tid >> 6, lane = tid & 63;
  int wrow = (w >> 1) * 64, wcol = (w & 1) * 64;
  int m0 = blockIdx.y * 128, n0 = blockIdx.x * 128;
  const int K = D_;
  f32x4 zero = {0.f,0.f,0.f,0.f};
  f32x4 acc[4][4];
  for (int i=0;i<4;i++) for (int j=0;j<4;j++) acc[i][j] = zero;

  for (int k0 = 0; k0 < K; k0 += BKg) {
    __syncthreads();
    for (int it = 0; it < 2; ++it) {
      int c = it*256 + tid;
      int row = c >> 2, cc = c & 3;
      int lbase = (it*256 + w*64) * 8;
      gl_lds16(Abf + (size_t)(m0+row)*K + k0 + cc*8, Al + lbase);
      gl_lds16(Bbf + (size_t)(n0+row)*K + k0 + cc*8, Bl + lbase);
    }
    asm volatile("s_waitcnt vmcnt(0)" ::: "memory");
    __syncthreads();
    int kof = (lane >> 4) * 8;
    bf16x8 af[4], bfr[4];
    for (int i=0;i<4;i++) af[i]  = *(const bf16x8*)(Al + (wrow + i*16 + (lane&15))*BKg + kof);
    for (int j=0;j<4;j++) bfr[j] = *(const bf16x8*)(Bl + (wcol + j*16 + (lane&15))*BKg + kof);
    for (int i=0;i<4;i++)
      for (int j=0;j<4;j++)
        acc[i][j] = __builtin_amdgcn_mfma_f32_16x16x32_bf16(af[i], bfr[j], acc[i][j], 0, 0, 0);
  }
  for (int i=0;i<4;i++)
    for (int j=0;j<4;j++)
      for (int r=0;r<4;r++) {
        int gm = m0 + wrow + i*16 + (lane>>4)*4 + r;
        int gn = n0 + wcol + j*16 + (lane&15);
        out[(size_t)gm*D_ + gn] = acc[i][j][r] + bias[gn];
      }
}

extern "C" void kernel_launch(void* const* d_in, const int* in_sizes, int n_in,
                              void* d_out, int out_size, void* d_ws, size_t ws_size,
                              hipStream_t stream) {
  const float* x  = (const float*)d_in[0];
  const float* Wi = (const float*)d_in[1];
  const float* bi = (const float*)d_in[2];
  const float* Wo = (const float*)d_in[3];
  const float* bo = (const float*)d_in[4];
  const int* causal = (const int*)d_in[5];
  float* out = (float*)d_out;

  ushort_t* xb   = (ushort_t*)d_ws;                       // 4096*1024 (reused as vtb)
  ushort_t* Wib  = xb  + (size_t)MTOT*D_;                 // 3072*1024
  ushort_t* Wob  = Wib + (size_t)NQKV*D_;                 // 1024*1024
  ushort_t* qbuf = Wob + (size_t)D_*D_;                   // 32*2048*64
  ushort_t* kbuf = qbuf + (size_t)B_*H_*S_*DH_;
  ushort_t* vbuf = kbuf + (size_t)B_*H_*S_*DH_;
  ushort_t* attnb = vbuf + (size_t)B_*H_*S_*DH_;          // 4096*1024
  ushort_t* vtb  = xb;  // xb dead after gemm_qkv; reuse for transposed V

  int n1 = MTOT*D_/8;
  cvt_kernel<<<(n1+255)/256, 256, 0, stream>>>(x, xb, n1);
  int n2 = NQKV*D_/8;
  cvt_kernel<<<(n2+255)/256, 256, 0, stream>>>(Wi, Wib, n2);
  int n3 = D_*D_/8;
  cvt_kernel<<<(n3+255)/256, 256, 0, stream>>>(Wo, Wob, n3);

  gemm_qkv<<<dim3(NQKV/128, MTOT/128), 256, 0, stream>>>(xb, Wib, bi, qbuf, kbuf, vbuf);
  transpose_v<<<dim3(S_/64, B_*H_), 256, 0, stream>>>(vbuf, vtb);
  attn_fwd<<<dim3(16, B_*H_), 256, 0, stream>>>(qbuf, kbuf, vtb, attnb, causal);
  gemm_out<<<dim3(D_/128, MTOT/128), 256, 0, stream>>>(attnb, Wob, bo, out);
}

// Round 4
// 121.666 us; speedup vs baseline: 1.9500x; 1.0996x over previous
//
#include <hip/hip_runtime.h>
#include <hip/hip_bf16.h>
#include <stdint.h>

#define B_    2
#define S_    2048
#define D_    1024
#define H_    16
#define DH_   64
#define MTOT  (B_*S_)     // 4096
#define NQKV  (3*D_)      // 3072

typedef __attribute__((ext_vector_type(8))) short  bf16x8;
typedef __attribute__((ext_vector_type(4))) float  f32x4;
typedef __attribute__((ext_vector_type(8))) unsigned short u16x8;
typedef unsigned short ushort_t;

__device__ __forceinline__ ushort_t f2bf(float f) {
  union { float f; unsigned int i; } v; v.f = f;
  unsigned int r = v.i + 0x7FFF + ((v.i >> 16) & 1);
  return (ushort_t)(r >> 16);
}

__device__ __forceinline__ unsigned cvt_pk_bf16(float lo, float hi) {
  unsigned r;
  asm("v_cvt_pk_bf16_f32 %0, %1, %2" : "=v"(r) : "v"(lo), "v"(hi));
  return r;
}

__device__ __forceinline__ float fexp2(float x) {
  float r;
  asm("v_exp_f32 %0, %1" : "=v"(r) : "v"(x));
  return r;
}

__device__ __forceinline__ void gl_lds16(const ushort_t* g, ushort_t* l) {
  __builtin_amdgcn_global_load_lds(
      (const __attribute__((address_space(1))) unsigned int*)g,
      (__attribute__((address_space(3))) unsigned int*)l, 16, 0, 0);
}

// ---------------- fused fp32 -> bf16 conversion (x, Wi, Wo) ----------------
#define CVN1 (MTOT*D_/8)
#define CVN2 (NQKV*D_/8)
#define CVN3 (D_*D_/8)
__global__ __launch_bounds__(256) void cvt_all(
    const float* __restrict__ x, const float* __restrict__ Wi, const float* __restrict__ Wo,
    ushort_t* __restrict__ xb, ushort_t* __restrict__ Wib, ushort_t* __restrict__ Wob) {
  int i = blockIdx.x * blockDim.x + threadIdx.x;
  const float* src; ushort_t* dst; int k;
  if (i < CVN1)            { src = x;  dst = xb;  k = i; }
  else if (i < CVN1+CVN2)  { src = Wi; dst = Wib; k = i - CVN1; }
  else                     { src = Wo; dst = Wob; k = i - CVN1 - CVN2; }
  const float4* s4 = (const float4*)src;
  float4 a = s4[2*k], b = s4[2*k+1];
  u16x8 o;
  o[0]=f2bf(a.x); o[1]=f2bf(a.y); o[2]=f2bf(a.z); o[3]=f2bf(a.w);
  o[4]=f2bf(b.x); o[5]=f2bf(b.y); o[6]=f2bf(b.z); o[7]=f2bf(b.w);
  ((u16x8*)dst)[k] = o;
}

// ---------------- QKV GEMM: qkv = x @ Wi^T + bi ----------------
#define BKg 32
// scale folded into q: 1/sqrt(64) * log2(e)  (exp2-domain softmax)
#define QSCALE 0.18033688011112042f
__global__ __launch_bounds__(256) void gemm_qkv(
    const ushort_t* __restrict__ Abf, const ushort_t* __restrict__ Bbf,
    const float* __restrict__ bias,
    ushort_t* __restrict__ qb, ushort_t* __restrict__ kb, ushort_t* __restrict__ vb) {
  __shared__ __align__(16) ushort_t Al[128*BKg];
  __shared__ __align__(16) ushort_t Bl[128*BKg];
  int tid = threadIdx.x;
  int w = tid >> 6, lane = tid & 63;
  int wrow = (w >> 1) * 64, wcol = (w & 1) * 64;
  int m0 = blockIdx.y * 128, n0 = blockIdx.x * 128;
  const int K = D_;
  f32x4 zero = {0.f, 0.f, 0.f, 0.f};
  f32x4 acc[4][4];
  for (int i=0;i<4;i++) for (int j=0;j<4;j++) acc[i][j] = zero;

  for (int k0 = 0; k0 < K; k0 += BKg) {
    __syncthreads();
    for (int it = 0; it < 2; ++it) {
      int c = it*256 + tid;
      int row = c >> 2, cc = c & 3;
      int lbase = (it*256 + w*64) * 8;
      gl_lds16(Abf + (size_t)(m0+row)*K + k0 + cc*8, Al + lbase);
      gl_lds16(Bbf + (size_t)(n0+row)*K + k0 + cc*8, Bl + lbase);
    }
    asm volatile("s_waitcnt vmcnt(0)" ::: "memory");
    __syncthreads();
    int kof = (lane >> 4) * 8;
    bf16x8 af[4], bfr[4];
    for (int i=0;i<4;i++) af[i]  = *(const bf16x8*)(Al + (wrow + i*16 + (lane&15))*BKg + kof);
    for (int j=0;j<4;j++) bfr[j] = *(const bf16x8*)(Bl + (wcol + j*16 + (lane&15))*BKg + kof);
    for (int i=0;i<4;i++)
      for (int j=0;j<4;j++)
        acc[i][j] = __builtin_amdgcn_mfma_f32_16x16x32_bf16(af[i], bfr[j], acc[i][j], 0, 0, 0);
  }
  for (int i=0;i<4;i++)
    for (int j=0;j<4;j++)
      for (int r=0;r<4;r++) {
        int gm = m0 + wrow + i*16 + (lane>>4)*4 + r;
        int gn = n0 + wcol + j*16 + (lane&15);
        float v = acc[i][j][r] + bias[gn];
        int b = gm >> 11, s = gm & (S_-1);
        int sect = gn >> 10, hn = gn & (D_-1);
        int hh = hn >> 6, d = hn & 63;
        size_t idx = (((size_t)(b*H_ + hh))*S_ + s)*DH_ + d;
        if (sect == 0) v *= QSCALE;
        ushort_t val = f2bf(v);
        if (sect == 0) qb[idx] = val;
        else if (sect == 1) kb[idx] = val;
        else vb[idx] = val;
      }
}

// ---------------- V transpose: [BH][S][DH] -> [BH][DH][S] ----------------
__global__ __launch_bounds__(256) void transpose_v(
    const ushort_t* __restrict__ vb, ushort_t* __restrict__ vtb) {
  __shared__ ushort_t T[64*72];
  int bh = blockIdx.y;
  int s0 = blockIdx.x * 64;
  int tid = threadIdx.x;
  const ushort_t* src = vb + (size_t)bh * S_ * DH_;
  ushort_t* dst = vtb + (size_t)bh * DH_ * S_;
  for (int it = 0; it < 2; ++it) {
    int c = it*256 + tid;
    int row = c >> 3, cc = c & 7;
    *(uint4*)&T[row*72 + cc*8] = *(const uint4*)(src + (size_t)(s0+row)*DH_ + cc*8);
  }
  __syncthreads();
  for (int it = 0; it < 2; ++it) {
    int c = it*256 + tid;
    int d = c >> 3, sc = c & 7;
    u16x8 o;
    #pragma unroll
    for (int e = 0; e < 8; ++e) o[e] = T[(sc*8+e)*72 + d];
    *(u16x8*)(dst + (size_t)d*S_ + s0 + sc*8) = o;
  }
}

// ---------------- flash attention v4 ----------------
// 1D grid 512: bh%8 == wgid%8 (XCD L2 locality); paired panels (p,31-p);
// 3-buffer KV pipeline, counted vmcnt(4); exp2-domain softmax + defer-max.
#define KVB 64
#define DTHR 8.0f
__global__ __launch_bounds__(256) void attn_fwd(
    const ushort_t* __restrict__ qb, const ushort_t* __restrict__ kb,
    const ushort_t* __restrict__ vtb, ushort_t* __restrict__ attnb,
    const int* __restrict__ causal) {
  int wg = blockIdx.x;                  // 0..511
  int xcd = wg & 7;
  int rest = wg >> 3;                   // 0..63
  int bh = (rest & 3) * 8 + xcd;        // same-bh blocks share an XCD
  int pairIdx = rest >> 2;              // 0..15
  int b = bh >> 4, h = bh & 15;
  int tid = threadIdx.x, w = tid >> 6, lane = tid & 63;
  int g = lane >> 4, q16 = lane & 15;
  const ushort_t* qh  = qb  + (size_t)bh * S_ * DH_;
  const ushort_t* kh  = kb  + (size_t)bh * S_ * DH_;
  const ushort_t* vth = vtb + (size_t)bh * DH_ * S_;
  __shared__ __align__(16) ushort_t Kl[3][KVB*64];
  __shared__ __align__(16) ushort_t Vtl[3][64*KVB];
  __shared__ __align__(16) ushort_t Pl[4][16*72];
  bool use_causal = (causal[0] != 0);

  int p1 = pairIdx, p2 = 31 - pairIdx;
  int nkv1 = use_causal ? (p1 + 1) : (S_/KVB);
  int nkv2 = use_causal ? (p2 + 1) : (S_/KVB);
  int total = nkv1 + nkv2;
  int qw1 = p1*64 + w*16, qw2 = p2*64 + w*16;

  // preload BOTH panels' Q fragments (keeps in-loop vmcnt counting exact)
  bf16x8 qA0 = *(const bf16x8*)(qh + (size_t)(qw1 + q16)*DH_ +  0 + g*8);
  bf16x8 qA1 = *(const bf16x8*)(qh + (size_t)(qw1 + q16)*DH_ + 32 + g*8);
  bf16x8 qB0 = *(const bf16x8*)(qh + (size_t)(qw2 + q16)*DH_ +  0 + g*8);
  bf16x8 qB1 = *(const bf16x8*)(qh + (size_t)(qw2 + q16)*DH_ + 32 + g*8);

  // staging: thread covers chunks c0=tid, c1=tid+256 of K and Vt tiles
  int c0 = tid, c1 = tid + 256;
  int r0 = c0 >> 3, sw0 = ((c0 & 7) ^ (r0 & 7)) * 8;
  int r1 = c1 >> 3, sw1 = ((c1 & 7) ^ (r1 & 7)) * 8;
  const ushort_t* kp0 = kh + r0*DH_ + sw0;
  const ushort_t* kp1 = kh + r1*DH_ + sw1;
  const ushort_t* vp0 = vth + (size_t)r0*S_ + sw0;
  const ushort_t* vp1 = vth + (size_t)r1*S_ + sw1;

  auto stage = [&](int it, int buf) {
    int t = (it < nkv1) ? it : (it - nkv1);
    size_t kadv = (size_t)(t*KVB) * DH_;
    int vadv = t*KVB;
    gl_lds16(kp0 + kadv, &Kl[buf][c0*8]);
    gl_lds16(kp1 + kadv, &Kl[buf][c1*8]);
    gl_lds16(vp0 + vadv, &Vtl[buf][c0*8]);
    gl_lds16(vp1 + vadv, &Vtl[buf][c1*8]);
  };

  f32x4 zero = {0.f,0.f,0.f,0.f};
  f32x4 o[4];
  #pragma unroll
  for (int dt=0;dt<4;dt++) o[dt] = zero;
  float mrun = -1e30f, lrun = 0.f;
  bf16x8 qc0 = qA0, qc1 = qA1;

  auto epilogue = [&](int qw) {
    float li0 = 1.f / __shfl(lrun, 4*g + 0, 64);
    float li1 = 1.f / __shfl(lrun, 4*g + 1, 64);
    float li2 = 1.f / __shfl(lrun, 4*g + 2, 64);
    float li3 = 1.f / __shfl(lrun, 4*g + 3, 64);
    #pragma unroll
    for (int r=0;r<4;r++) {
      float li = (r==0)?li0:(r==1)?li1:(r==2)?li2:li3;
      int q = qw + 4*g + r;
      #pragma unroll
      for (int dt=0;dt<4;dt++) {
        int d = dt*16 + q16;
        attnb[((size_t)(b*S_ + q))*D_ + h*DH_ + d] = f2bf(o[dt][r] * li);
      }
    }
  };

  // prologue: stage it=0,1 (total >= 33 always)
  stage(0, 0);
  stage(1, 1);
  asm volatile("s_waitcnt vmcnt(4)" ::: "memory");
  __syncthreads();

  for (int it = 0; it < total; ++it) {
    if (it == nkv1) {  // panel switch
      epilogue(qw1);
      #pragma unroll
      for (int dt=0;dt<4;dt++) o[dt] = zero;
      mrun = -1e30f; lrun = 0.f;
      qc0 = qB0; qc1 = qB1;
    }
    int t    = (it < nkv1) ? it : (it - nkv1);
    int nkvc = (it < nkv1) ? nkv1 : nkv2;
    int cur = it % 3;
    if (it + 2 < total) stage(it + 2, (it + 2) % 3);

    // ---- QK^T swapped: col=q16(q), row=4g+r(kv) ----
    f32x4 sacc[4];
    #pragma unroll
    for (int j=0;j<4;j++) sacc[j] = zero;
    #pragma unroll
    for (int kk=0;kk<2;kk++) {
      bf16x8 qf = kk ? qc1 : qc0;
      #pragma unroll
      for (int j=0;j<4;j++) {
        int row = j*16 + q16;
        int slot = (kk*4 + g) ^ (row & 7);
        bf16x8 kf = *(const bf16x8*)(&Kl[cur][row*64 + slot*8]);
        sacc[j] = __builtin_amdgcn_mfma_f32_16x16x32_bf16(kf, qf, sacc[j], 0, 0, 0);
      }
    }
    // ---- causal mask on the diagonal tile ----
    if (use_causal && t == nkvc-1) {
      int qrel = 16*w + q16;
      #pragma unroll
      for (int j=0;j<4;j++)
        #pragma unroll
        for (int r=0;r<4;r++)
          if (16*j + 4*g + r > qrel) sacc[j][r] = -1e30f;
    }
    // ---- online softmax (exp2 domain), defer-max ----
    float m0v = fmaxf(fmaxf(sacc[0][0], sacc[0][1]), fmaxf(sacc[0][2], sacc[0][3]));
    float m1v = fmaxf(fmaxf(sacc[1][0], sacc[1][1]), fmaxf(sacc[1][2], sacc[1][3]));
    float m2v = fmaxf(fmaxf(sacc[2][0], sacc[2][1]), fmaxf(sacc[2][2], sacc[2][3]));
    float m3v = fmaxf(fmaxf(sacc[3][0], sacc[3][1]), fmaxf(sacc[3][2], sacc[3][3]));
    float mx = fmaxf(fmaxf(m0v, m1v), fmaxf(m2v, m3v));
    mx = fmaxf(mx, __shfl_xor(mx, 16, 64));
    mx = fmaxf(mx, __shfl_xor(mx, 32, 64));
    if (!__all(mx - mrun <= DTHR)) {
      float mnew = fmaxf(mrun, mx);
      float alpha = fexp2(mrun - mnew);
      lrun *= alpha;
      float av0 = __shfl(alpha, 4*g + 0, 64);
      float av1 = __shfl(alpha, 4*g + 1, 64);
      float av2 = __shfl(alpha, 4*g + 2, 64);
      float av3 = __shfl(alpha, 4*g + 3, 64);
      #pragma unroll
      for (int dt=0;dt<4;dt++) {
        o[dt][0] *= av0; o[dt][1] *= av1; o[dt][2] *= av2; o[dt][3] *= av3;
      }
      mrun = mnew;
    }
    float p[4][4];
    float rs = 0.f;
    #pragma unroll
    for (int j=0;j<4;j++)
      #pragma unroll
      for (int r=0;r<4;r++) {
        p[j][r] = fexp2(sacc[j][r] - mrun);
        rs += p[j][r];
      }
    rs += __shfl_xor(rs, 16, 64);
    rs += __shfl_xor(rs, 32, 64);
    lrun += rs;
    // ---- pack P into Pl[w] ----
    #pragma unroll
    for (int j=0;j<4;j++) {
      uint2 pw;
      pw.x = cvt_pk_bf16(p[j][0], p[j][1]);
      pw.y = cvt_pk_bf16(p[j][2], p[j][3]);
      *(uint2*)&Pl[w][q16*72 + j*16 + g*4] = pw;
    }
    // ---- PV: O += P(16x64) V(64x64) ----
    #pragma unroll
    for (int kk=0;kk<2;kk++) {
      bf16x8 pf = *(const bf16x8*)&Pl[w][q16*72 + kk*32 + g*8];
      #pragma unroll
      for (int dt=0;dt<4;dt++) {
        int row = dt*16 + q16;
        int slot = (kk*4 + g) ^ (row & 7);
        bf16x8 vf = *(const bf16x8*)(&Vtl[cur][row*64 + slot*8]);
        o[dt] = __builtin_amdgcn_mfma_f32_16x16x32_bf16(pf, vf, o[dt], 0, 0, 0);
      }
    }
    // ---- counted wait: next tile must be ready; 2-ahead stays in flight ----
    if (it + 2 < total) {
      asm volatile("s_waitcnt vmcnt(4)" ::: "memory");
    } else {
      asm volatile("s_waitcnt vmcnt(0)" ::: "memory");
    }
    __syncthreads();
  }
  epilogue(qw2);
}

// ---------------- output GEMM: out = attn @ Wo^T + bo (fp32 out) ----------------
__global__ __launch_bounds__(256) void gemm_out(
    const ushort_t* __restrict__ Abf, const ushort_t* __restrict__ Bbf,
    const float* __restrict__ bias, float* __restrict__ out) {
  __shared__ __align__(16) ushort_t Al[128*BKg];
  __shared__ __align__(16) ushort_t Bl[128*BKg];
  int tid = threadIdx.x;
  int w = tid >> 6, lane = tid & 63;
  int wrow = (w >> 1) * 64, wcol = (w & 1) * 64;
  int m0 = blockIdx.y * 128, n0 = blockIdx.x * 128;
  const int K = D_;
  f32x4 zero = {0.f,0.f,0.f,0.f};
  f32x4 acc[4][4];
  for (int i=0;i<4;i++) for (int j=0;j<4;j++) acc[i][j] = zero;

  for (int k0 = 0; k0 < K; k0 += BKg) {
    __syncthreads();
    for (int it = 0; it < 2; ++it) {
      int c = it*256 + tid;
      int row = c >> 2, cc = c & 3;
      int lbase = (it*256 + w*64) * 8;
      gl_lds16(Abf + (size_t)(m0+row)*K + k0 + cc*8, Al + lbase);
      gl_lds16(Bbf + (size_t)(n0+row)*K + k0 + cc*8, Bl + lbase);
    }
    asm volatile("s_waitcnt vmcnt(0)" ::: "memory");
    __syncthreads();
    int kof = (lane >> 4) * 8;
    bf16x8 af[4], bfr[4];
    for (int i=0;i<4;i++) af[i]  = *(const bf16x8*)(Al + (wrow + i*16 + (lane&15))*BKg + kof);
    for (int j=0;j<4;j++) bfr[j] = *(const bf16x8*)(Bl + (wcol + j*16 + (lane&15))*BKg + kof);
    for (int i=0;i<4;i++)
      for (int j=0;j<4;j++)
        acc[i][j] = __builtin_amdgcn_mfma_f32_16x16x32_bf16(af[i], bfr[j], acc[i][j], 0, 0, 0);
  }
  for (int i=0;i<4;i++)
    for (int j=0;j<4;j++)
      for (int r=0;r<4;r++) {
        int gm = m0 + wrow + i*16 + (lane>>4)*4 + r;
        int gn = n0 + wcol + j*16 + (lane&15);
        out[(size_t)gm*D_ + gn] = acc[i][j][r] + bias[gn];
      }
}

extern "C" void kernel_launch(void* const* d_in, const int* in_sizes, int n_in,
                              void* d_out, int out_size, void* d_ws, size_t ws_size,
                              hipStream_t stream) {
  const float* x  = (const float*)d_in[0];
  const float* Wi = (const float*)d_in[1];
  const float* bi = (const float*)d_in[2];
  const float* Wo = (const float*)d_in[3];
  const float* bo = (const float*)d_in[4];
  const int* causal = (const int*)d_in[5];
  float* out = (float*)d_out;

  ushort_t* xb   = (ushort_t*)d_ws;                       // 4096*1024 (reused as vtb)
  ushort_t* Wib  = xb  + (size_t)MTOT*D_;                 // 3072*1024
  ushort_t* Wob  = Wib + (size_t)NQKV*D_;                 // 1024*1024
  ushort_t* qbuf = Wob + (size_t)D_*D_;                   // 32*2048*64
  ushort_t* kbuf = qbuf + (size_t)B_*H_*S_*DH_;
  ushort_t* vbuf = kbuf + (size_t)B_*H_*S_*DH_;
  ushort_t* attnb = vbuf + (size_t)B_*H_*S_*DH_;          // 4096*1024
  ushort_t* vtb  = xb;  // xb dead after gemm_qkv; reuse for transposed V

  int ntot = CVN1 + CVN2 + CVN3;
  cvt_all<<<(ntot+255)/256, 256, 0, stream>>>(x, Wi, Wo, xb, Wib, Wob);

  gemm_qkv<<<dim3(NQKV/128, MTOT/128), 256, 0, stream>>>(xb, Wib, bi, qbuf, kbuf, vbuf);
  transpose_v<<<dim3(S_/64, B_*H_), 256, 0, stream>>>(vbuf, vtb);
  attn_fwd<<<512, 256, 0, stream>>>(qbuf, kbuf, vtb, attnb, causal);
  gemm_out<<<dim3(D_/128, MTOT/128), 256, 0, stream>>>(attnb, Wob, bo, out);
}